// Round 19
// baseline (241.763 us; speedup 1.0000x reference)
//
#include <hip/hip_runtime.h>
#include <stdint.h>

// ---------------------------------------------------------------------------
// GeometricAttention: x@Wqkv (+fused RoPE/V-transpose epilogue) -> causal MHA
// (split-K chunks, ZERO-barrier direct-from-global K/V fragments, + merge)
// -> @Wo (split-K) -> blade mixing (float4).
// B=2 T=2048 N=8 D=128, d_model=1024. bf16 MFMA pipeline, fp32 accum.
// ---------------------------------------------------------------------------

typedef __attribute__((ext_vector_type(8)))  __bf16 bf16x8;
typedef __attribute__((ext_vector_type(8)))  uint16_t u16x8;
typedef __attribute__((ext_vector_type(4)))  float  f32x4;

__device__ __forceinline__ uint16_t f2bf(float f) {
    uint32_t u = __float_as_uint(f);
    u += 0x7FFFu + ((u >> 16) & 1u);           // RNE
    return (uint16_t)(u >> 16);
}
__device__ __forceinline__ float bf2f(uint16_t h) {
    return __uint_as_float(((uint32_t)h) << 16);
}

__device__ __forceinline__ void gload_lds16(const void* g, void* l) {
    __builtin_amdgcn_global_load_lds(
        (__attribute__((address_space(1))) void*)g,
        (__attribute__((address_space(3))) void*)l, 16, 0, 0);
}

// ----------------------- fused prologue: cast / weight-transpose / rope tables
__global__ __launch_bounds__(256) void k_prep(const float* __restrict__ mv,
                                              const float* __restrict__ Wqkv,
                                              const float* __restrict__ Wo,
                                              uint16_t* __restrict__ Xbf,
                                              uint16_t* __restrict__ Wqt,
                                              uint16_t* __restrict__ Wot,
                                              float* __restrict__ ct,
                                              float* __restrict__ st) {
    __shared__ uint16_t tile[64][65];
    const int bid = blockIdx.x;
    const int tid = threadIdx.x;
    if (bid < 4096) {                                // cast
        int i = bid * 256 + tid;
        float4 v = ((const float4*)mv)[i];
        ((ushort4*)Xbf)[i] = make_ushort4(f2bf(v.x), f2bf(v.y), f2bf(v.z), f2bf(v.w));
    } else if (bid < 5120) {                         // weight transpose
        const float* W; uint16_t* Wt; int N, bx, by;
        if (bid < 4864) { W = Wqkv; Wt = Wqt; N = 3072;
                          int b2 = bid - 4096; bx = b2 % 48; by = b2 / 48; }
        else            { W = Wo;   Wt = Wot; N = 1024;
                          int b3 = bid - 4864; bx = b3 & 15; by = b3 >> 4; }
        const int k0 = by * 64, n0 = bx * 64;
        const int c = tid & 63, r4 = tid >> 6;
#pragma unroll
        for (int i = 0; i < 16; ++i) {
            int r = r4 + i * 4;
            tile[r][c] = f2bf(W[(size_t)(k0 + r) * N + n0 + c]);
        }
        __syncthreads();
#pragma unroll
        for (int i = 0; i < 16; ++i) {
            int r = r4 + i * 4;
            Wt[(size_t)(n0 + r) * 1024 + k0 + c] = tile[c][r];
        }
    } else {                                         // rope tables
        int i = (bid - 5120) * 256 + tid;            // 2048*64
        int t = i >> 6, f = i & 63;
        float inv = expf(-(float)f * 0.14391156830441f); // ln(10000)/64
        float ang = (float)t * inv;
        ct[i] = cosf(ang);
        st[i] = sinf(ang);
    }
}

// ---------------------- QKV GEMM (BK=64, swizzled LDS) + RoPE/V-T epilogue
__global__ __launch_bounds__(256) void k_gemmqkv(const uint16_t* __restrict__ A,
                                                 const uint16_t* __restrict__ Bt,
                                                 const float* __restrict__ ct,
                                                 const float* __restrict__ st,
                                                 uint16_t* __restrict__ Qr,
                                                 uint16_t* __restrict__ Kr,
                                                 uint16_t* __restrict__ Vt) {
    __shared__ __align__(16) char smem[33792];       // loop: 32KB A+B; epi: Tl
    uint16_t* Atile = (uint16_t*)smem;               // [128][64] swizzled
    uint16_t* Btile = (uint16_t*)(smem + 16384);     // [128][64] swizzled
    const int lin = blockIdx.y * 24 + blockIdx.x;
    const int logical = (lin & 7) * 96 + (lin >> 3); // XCD swizzle (bijective)
    const int bx = logical % 24;                     // n-tile 0..23
    const int m0 = (logical / 24) << 7, n0 = bx << 7;
    const int sec = bx >> 3, head = bx & 7;
    const int tid = threadIdx.x;
    const int l = tid & 63, w = tid >> 6;
    const int lr = l & 15, lg = l >> 4;
    const int wm = (w >> 1) << 6, wn = (w & 1) << 6;
    const int K = 1024;

    f32x4 acc[4][4];
#pragma unroll
    for (int i = 0; i < 4; ++i)
#pragma unroll
        for (int j = 0; j < 4; ++j) acc[i][j] = (f32x4){0.f, 0.f, 0.f, 0.f};

    for (int kt = 0; kt < 16; ++kt) {                // K = 16 x 64
        const int k0 = kt << 6;
        __syncthreads();
#pragma unroll
        for (int c = 0; c < 8; ++c) {                // 2048 16B chunks
            int idx = c * 256 + tid;
            if (idx < 1024) {                        // A: row r, chunk c16
                int r = idx >> 3, c16 = idx & 7;
                int sc = c16 ^ (r & 7);              // inverse swizzle on SOURCE
                gload_lds16(A + (size_t)(m0 + r) * K + k0 + sc * 8, Atile + idx * 8);
            } else {
                int i2 = idx - 1024;
                int r = i2 >> 3, c16 = i2 & 7;
                int sc = c16 ^ (r & 7);
                gload_lds16(Bt + (size_t)(n0 + r) * K + k0 + sc * 8, Btile + i2 * 8);
            }
        }
        __syncthreads();
#pragma unroll
        for (int kk = 0; kk < 2; ++kk) {
            bf16x8 af[4], bfv[4];
#pragma unroll
            for (int i = 0; i < 4; ++i) {
                int ra = wm + i * 16 + lr;
                af[i]  = *(const bf16x8*)((char*)Atile + ra * 128 +
                          ((kk * 64 + lg * 16) ^ ((ra & 7) << 4)));
                int rb = wn + i * 16 + lr;
                bfv[i] = *(const bf16x8*)((char*)Btile + rb * 128 +
                          ((kk * 64 + lg * 16) ^ ((rb & 7) << 4)));
            }
#pragma unroll
            for (int mi = 0; mi < 4; ++mi)
#pragma unroll
                for (int ni = 0; ni < 4; ++ni)
                    acc[mi][ni] = __builtin_amdgcn_mfma_f32_16x16x32_bf16(
                        af[mi], bfv[ni], acc[mi][ni], 0, 0, 0);
        }
    }

    // ---- epilogue: acc -> LDS bf16 tile (overlays Atile/Btile)
    __syncthreads();
    uint16_t (*Tl)[132] = (uint16_t(*)[132])smem;    // [128][132], 33792 B
#pragma unroll
    for (int mi = 0; mi < 4; ++mi)
#pragma unroll
        for (int ni = 0; ni < 4; ++ni)
#pragma unroll
            for (int r = 0; r < 4; ++r)
                Tl[wm + mi * 16 + lg * 4 + r][wn + ni * 16 + lr] =
                    f2bf(acc[mi][ni][r]);
    __syncthreads();

    const int b = m0 >> 11, t0 = m0 & 2047;
    const size_t hidx = (size_t)(b * 8 + head);
    if (sec < 2) {                                   // Q or K: rope + write
        uint16_t* outp = (sec == 0 ? Qr : Kr) + (hidx * 2048 + t0) * 128;
#pragma unroll
        for (int it = 0; it < 8; ++it) {
            int lin2 = it * 256 + tid;
            int tr = lin2 >> 4, d0 = (lin2 & 15) * 4;
            ushort4 lo = *(const ushort4*)&Tl[tr][d0];
            ushort4 hi = *(const ushort4*)&Tl[tr][d0 + 64];
            float4 cv = *(const float4*)&ct[(size_t)(t0 + tr) * 64 + d0];
            float4 sv = *(const float4*)&st[(size_t)(t0 + tr) * 64 + d0];
            ushort4 o1, o2;
            o1.x = f2bf(bf2f(lo.x) * cv.x - bf2f(hi.x) * sv.x);
            o2.x = f2bf(bf2f(hi.x) * cv.x + bf2f(lo.x) * sv.x);
            o1.y = f2bf(bf2f(lo.y) * cv.y - bf2f(hi.y) * sv.y);
            o2.y = f2bf(bf2f(hi.y) * cv.y + bf2f(lo.y) * sv.y);
            o1.z = f2bf(bf2f(lo.z) * cv.z - bf2f(hi.z) * sv.z);
            o2.z = f2bf(bf2f(hi.z) * cv.z + bf2f(lo.z) * sv.z);
            o1.w = f2bf(bf2f(lo.w) * cv.w - bf2f(hi.w) * sv.w);
            o2.w = f2bf(bf2f(hi.w) * cv.w + bf2f(lo.w) * sv.w);
            *(ushort4*)&outp[(size_t)tr * 128 + d0]      = o1;
            *(ushort4*)&outp[(size_t)tr * 128 + d0 + 64] = o2;
        }
    } else {                                         // V: transpose to [h][D][T]
        uint16_t* vp = Vt + hidx * 128 * 2048;
#pragma unroll
        for (int it = 0; it < 8; ++it) {
            int lin2 = it * 256 + tid;
            int d = lin2 >> 4, tq = (lin2 & 15) * 8;
            ushort4 v0 = make_ushort4(Tl[tq + 0][d], Tl[tq + 1][d],
                                      Tl[tq + 2][d], Tl[tq + 3][d]);
            ushort4 v1 = make_ushort4(Tl[tq + 4][d], Tl[tq + 5][d],
                                      Tl[tq + 6][d], Tl[tq + 7][d]);
            *(ushort4*)&vp[(size_t)d * 2048 + t0 + tq]     = v0;
            *(ushort4*)&vp[(size_t)d * 2048 + t0 + tq + 4] = v1;
        }
    }
}

// ------------------- split-K out-proj GEMM, 128x64 tiles, BK=64, swizzled
__global__ __launch_bounds__(256) void k_gemm2s(const uint16_t* __restrict__ A,
                                                const uint16_t* __restrict__ Bt,
                                                float* __restrict__ C) {
    __shared__ uint16_t Atile[128 * 64];             // 16 KB swizzled
    __shared__ uint16_t Btile[64 * 64];              //  8 KB swizzled
    const int kz = blockIdx.z;
    A  += (size_t)kz * 512;                          // k-offset within row
    Bt += (size_t)kz * 512;
    C  += (size_t)kz * (4096u * 1024u);              // partial-output buffer
    const int lin = blockIdx.y * 16 + blockIdx.x;
    const int logical = (lin & 7) * 64 + (lin >> 3); // XCD swizzle per z
    const int m0 = (logical >> 4) << 7, n0 = (logical & 15) << 6;
    const int tid = threadIdx.x;
    const int l = tid & 63, w = tid >> 6;
    const int lr = l & 15, lg = l >> 4;
    const int wm = (w >> 1) << 6, wn = (w & 1) << 5;

    f32x4 acc[4][2];
#pragma unroll
    for (int i = 0; i < 4; ++i)
#pragma unroll
        for (int j = 0; j < 2; ++j) acc[i][j] = (f32x4){0.f, 0.f, 0.f, 0.f};

    for (int kt = 0; kt < 8; ++kt) {                 // K_half = 512 = 8 x 64
        const int k0 = kt << 6;
        __syncthreads();
#pragma unroll
        for (int c = 0; c < 6; ++c) {                // 1536 16B chunks
            int idx = c * 256 + tid;
            if (idx < 1024) {                        // A: 128 rows x 8 chunks
                int r = idx >> 3, c16 = idx & 7;
                int sc = c16 ^ (r & 7);
                gload_lds16(A + (size_t)(m0 + r) * 1024 + k0 + sc * 8, Atile + idx * 8);
            } else {                                 // B: 64 rows x 8 chunks
                int i2 = idx - 1024;
                int r = i2 >> 3, c16 = i2 & 7;
                int sc = c16 ^ (r & 7);
                gload_lds16(Bt + (size_t)(n0 + r) * 1024 + k0 + sc * 8, Btile + i2 * 8);
            }
        }
        __syncthreads();
#pragma unroll
        for (int kk = 0; kk < 2; ++kk) {
            bf16x8 af[4], bfv[2];
#pragma unroll
            for (int i = 0; i < 4; ++i) {
                int ra = wm + i * 16 + lr;
                af[i] = *(const bf16x8*)((char*)Atile + ra * 128 +
                         ((kk * 64 + lg * 16) ^ ((ra & 7) << 4)));
            }
#pragma unroll
            for (int j = 0; j < 2; ++j) {
                int rb = wn + j * 16 + lr;
                bfv[j] = *(const bf16x8*)((char*)Btile + rb * 128 +
                          ((kk * 64 + lg * 16) ^ ((rb & 7) << 4)));
            }
#pragma unroll
            for (int mi = 0; mi < 4; ++mi)
#pragma unroll
                for (int ni = 0; ni < 2; ++ni)
                    acc[mi][ni] = __builtin_amdgcn_mfma_f32_16x16x32_bf16(
                        af[mi], bfv[ni], acc[mi][ni], 0, 0, 0);
        }
    }
#pragma unroll
    for (int mi = 0; mi < 4; ++mi)
#pragma unroll
        for (int ni = 0; ni < 2; ++ni)
#pragma unroll
            for (int r = 0; r < 4; ++r) {
                int row = m0 + wm + mi * 16 + lg * 4 + r;
                int col = n0 + wn + ni * 16 + lr;
                C[(size_t)row * 1024 + col] = acc[mi][ni][r];
            }
}

// --------------------------------------------------- causal flash attention
// R19: ZERO-barrier variant. K and V MFMA fragments are loaded DIRECTLY from
// global (both are 16B-contiguous in the existing layouts: K[h][T][128] A-frag
// = (k_row)*128 + kc*32+lg*8; Vt[h][128][T] B-frag = d*2048 + kt*64+c*32+lg*8),
// double-buffered in registers per cg/ni step. No STAGE, no vmcnt, no
// s_barrier — waves fully independent; LDS holds only the per-wave P buffer
// (8 KB). Residency becomes VGPR-capped (~3-4 waves/SIMD, ~2x the measured
// average of the barrier version). Cost: K/V read from L2 per wave (4x
// amplification, ~24 TB/s demand vs 34 TB/s ceiling) — measured gamble.
// Chunking/decode/epilogue identical to R18.
__global__ __launch_bounds__(256) void k_attn(const uint16_t* __restrict__ Qg,
                                              const uint16_t* __restrict__ Kg,
                                              const uint16_t* __restrict__ Vtg,
                                              uint16_t* __restrict__ pbuf,
                                              float* __restrict__ mlg,
                                              uint16_t* __restrict__ AOg) {
    __shared__ uint16_t Plds[4][16 * 64];            // 8 KB, per-wave only

    const int h = blockIdx.x;
    const int y = blockIdx.y;                        // 0..47
    const int qt = (y < 32) ? (31 - (y >> 1)) : (47 - y);
    const int ci = (y < 32) ? (y & 1) : 0;
    const int slot = h * 48 + y;
    const int p0 = ci * 16;
    const int pend = min(p0 + 16, qt + 1);
    const int q0 = qt * 64;
    const int tid = threadIdx.x;
    const int l = tid & 63, w = tid >> 6;
    const int lr = l & 15, lg = l >> 4;
    const size_t headTD = (size_t)h * (2048 * 128);
    const uint16_t* Kh = Kg + headTD;
    const uint16_t* Vh = Vtg + headTD;

    bf16x8 qf[4];
    {
        const uint16_t* qp = Qg + headTD + (size_t)(q0 + w * 16 + lr) * 128 + lg * 8;
#pragma unroll
        for (int kc = 0; kc < 4; ++kc) qf[kc] = *(const bf16x8*)(qp + kc * 32);
    }

    f32x4 accO[8];
#pragma unroll
    for (int i = 0; i < 8; ++i) accO[i] = (f32x4){0.f, 0.f, 0.f, 0.f};
    float mrun = -1e30f, lrun = 0.f;                 // per-lane row q = lr

    const float SL2E = 0.08838834764831845f * 1.4426950408889634f; // scale*log2e
    const int   swz  = (lr & 7) << 4;                // P swizzle (row=lr)
    uint16_t* Pw = &Plds[w][0];

    for (int kt = p0; kt < pend; ++kt) {
        const uint16_t* Kt = Kh + (size_t)(kt * 64) * 128 + lg * 8; // +row*128
        const uint16_t* Vt0 = Vh + (size_t)lr * 2048 + kt * 64 + lg * 8; // +ni*16*2048

        // ---- S^T = K Q^T, K A-frags direct from global (reg dbuf by cg) --
        float sv[4][4];
        bf16x8 kA[4], kB[4];
#pragma unroll
        for (int kc = 0; kc < 4; ++kc)               // cg = 0
            kA[kc] = *(const bf16x8*)(Kt + (size_t)lr * 128 + kc * 32);
#pragma unroll
        for (int cg = 0; cg < 4; ++cg) {
            bf16x8* cur = (cg & 1) ? kB : kA;
            bf16x8* nxt = (cg & 1) ? kA : kB;
            if (cg < 3) {
#pragma unroll
                for (int kc = 0; kc < 4; ++kc)
                    nxt[kc] = *(const bf16x8*)(Kt + (size_t)((cg + 1) * 16 + lr) * 128 + kc * 32);
            }
            f32x4 a = (f32x4){0.f, 0.f, 0.f, 0.f};
#pragma unroll
            for (int kc = 0; kc < 4; ++kc)
                a = __builtin_amdgcn_mfma_f32_16x16x32_bf16(cur[kc], qf[kc], a, 0, 0, 0);
#pragma unroll
            for (int r = 0; r < 4; ++r) sv[cg][r] = a[r];
        }

        if (kt == qt) {                              // causal mask, diagonal tile
#pragma unroll
            for (int cg = 0; cg < 4; ++cg)
#pragma unroll
                for (int r = 0; r < 4; ++r)
                    if (cg * 16 + lg * 4 + r > w * 16 + lr) sv[cg][r] = -1e30f;
        }

        // ---- defer-max online softmax (lane-local row) -------------------
        float pml = sv[0][0];
#pragma unroll
        for (int cg = 0; cg < 4; ++cg)
#pragma unroll
            for (int r = 0; r < 4; ++r) pml = fmaxf(pml, sv[cg][r]);

        if (!__all(pml * SL2E <= mrun + 11.f)) {     // rare: true max + rescale
            float mx = pml;
            mx = fmaxf(mx, __shfl_xor(mx, 16, 64));
            mx = fmaxf(mx, __shfl_xor(mx, 32, 64));  // full row max (q = lr)
            float mn = fmaxf(mrun, mx * SL2E);
            float corr = exp2f(mrun - mn);
            mrun = mn;
            lrun *= corr;                            // lane-partial sum scales too
            float ca[4];
#pragma unroll
            for (int r = 0; r < 4; ++r)              // corr for accO rows q=lg*4+r
                ca[r] = __shfl(corr, (lg << 4) + lg * 4 + r, 64);
#pragma unroll
            for (int i = 0; i < 8; ++i)
#pragma unroll
                for (int r = 0; r < 4; ++r) accO[i][r] *= ca[r];
        }

        float psum = 0.f;
        float p[4][4];
#pragma unroll
        for (int cg = 0; cg < 4; ++cg)
#pragma unroll
            for (int r = 0; r < 4; ++r) {
                p[cg][r] = exp2f(fmaf(sv[cg][r], SL2E, -mrun));
                psum += p[cg][r];
            }
        lrun += psum;

        // pack P pairs -> b64 LDS writes (row q=lr, k = 16cg+4lg .. +3)
#pragma unroll
        for (int cg = 0; cg < 4; ++cg) {
            uint32_t w0, w1;
            asm("v_cvt_pk_bf16_f32 %0, %1, %2" : "=v"(w0) : "v"(p[cg][0]), "v"(p[cg][1]));
            asm("v_cvt_pk_bf16_f32 %0, %1, %2" : "=v"(w1) : "v"(p[cg][2]), "v"(p[cg][3]));
            uint2 pr; pr.x = w0; pr.y = w1;
            *(uint2*)((char*)Pw + lr * 128 + ((cg * 32 + lg * 8) ^ swz)) = pr;
        }

        asm volatile("" ::: "memory");               // order P stores before reads
        bf16x8 pf[2];
#pragma unroll
        for (int c = 0; c < 2; ++c)
            pf[c] = *(const bf16x8*)((char*)Pw + lr * 128 + ((c * 64 + lg * 16) ^ swz));

        // ---- O += P V, V B-frags direct from global (reg dbuf by ni) -----
        bf16x8 vA[2], vB[2];
        vA[0] = *(const bf16x8*)(Vt0);               // ni = 0, c = 0
        vA[1] = *(const bf16x8*)(Vt0 + 32);          // ni = 0, c = 1
#pragma unroll
        for (int ni = 0; ni < 8; ++ni) {
            bf16x8* cur = (ni & 1) ? vB : vA;
            bf16x8* nxt = (ni & 1) ? vA : vB;
            if (ni < 7) {
                const uint16_t* vp = Vt0 + (size_t)((ni + 1) * 16) * 2048;
                nxt[0] = *(const bf16x8*)(vp);
                nxt[1] = *(const bf16x8*)(vp + 32);
            }
#pragma unroll
            for (int c = 0; c < 2; ++c)
                accO[ni] = __builtin_amdgcn_mfma_f32_16x16x32_bf16(pf[c], cur[c], accO[ni], 0, 0, 0);
        }
    }

    // ---- epilogue ---------------------------------------------------------
    float lsum = lrun;
    lsum += __shfl_xor(lsum, 16, 64);
    lsum += __shfl_xor(lsum, 32, 64);                // full sum for row q = lr

    if (qt <= 15) {                                  // single chunk: direct AO
        float linv = 1.f / lsum;
        float inv[4];
#pragma unroll
        for (int r = 0; r < 4; ++r)
            inv[r] = __shfl(linv, (lg << 4) + lg * 4 + r, 64);
        const int b = h >> 3, n = h & 7;
#pragma unroll
        for (int ni = 0; ni < 8; ++ni)
#pragma unroll
            for (int r = 0; r < 4; ++r) {
                int trow = q0 + w * 16 + lg * 4 + r;
                AOg[((size_t)(b * 2048 + trow)) * 1024 + n * 128 + ni * 16 + lr] =
                    f2bf(accO[ni][r] * inv[r]);
            }
    } else {                                         // partial + (m, l)
        uint16_t* pb = pbuf + (size_t)slot * 8192;
#pragma unroll
        for (int ni = 0; ni < 8; ++ni)
#pragma unroll
            for (int r = 0; r < 4; ++r) {
                int row = w * 16 + lg * 4 + r;
                pb[row * 128 + ni * 16 + lr] = f2bf(accO[ni][r]);
            }
        if (lg == 0) {                               // one lane per (w,lr) row
            mlg[slot * 128 + w * 16 + lr]      = mrun;   // scaled-log2 domain
            mlg[slot * 128 + 64 + w * 16 + lr] = lsum;
        }
    }
}

// ------------------------------- split-K partial merge -> AO (qt >= 16, nc=2)
__global__ __launch_bounds__(256) void k_amerge(const uint16_t* __restrict__ pbuf,
                                                const float* __restrict__ mlg,
                                                uint16_t* __restrict__ AOg) {
    const int h = blockIdx.x, qt = 16 + blockIdx.y;  // qt in [16, 31]
    const int slot0 = h * 48 + 2 * (31 - qt);        // y = 2*(31-qt), +1
    const int tid = threadIdx.x;
    const int row = tid >> 2, dq = (tid & 3) * 32;

    float m0 = mlg[slot0 * 128 + row];
    float m1 = mlg[(slot0 + 1) * 128 + row];
    float M  = fmaxf(m0, m1);
    float w0 = exp2f(m0 - M), w1 = exp2f(m1 - M);
    float L  = mlg[slot0 * 128 + 64 + row] * w0 +
               mlg[(slot0 + 1) * 128 + 64 + row] * w1;
    float inv = 1.f / L;
    w0 *= inv; w1 *= inv;

    const u16x8* p0 = (const u16x8*)(pbuf + (size_t)slot0 * 8192 + row * 128 + dq);
    const u16x8* p1 = (const u16x8*)(pbuf + (size_t)(slot0 + 1) * 8192 + row * 128 + dq);
    const int b = h >> 3, n = h & 7;
    uint16_t* op = AOg + ((size_t)(b * 2048 + qt * 64 + row)) * 1024 + n * 128 + dq;
#pragma unroll
    for (int jj = 0; jj < 4; ++jj) {
        u16x8 a = p0[jj], c = p1[jj], v;
#pragma unroll
        for (int k = 0; k < 8; ++k)
            v[k] = f2bf(bf2f(a[k]) * w0 + bf2f(c[k]) * w1);
        ((u16x8*)op)[jj] = v;
    }
}

// ------------------------------- blade mixing epilogue (float4 + split-K add)
__global__ __launch_bounds__(256) void k_mix(const float* __restrict__ out0,
                                             const float* __restrict__ out1,
                                             const float* __restrict__ alpha,
                                             float* __restrict__ fin) {
    constexpr int SI[42] = {1,1,1,1,1,1, 2,2,2,2,2,2, 3,3,3,3,3,3, 4,4,4,4,4,4,
                            5,5,5,5,5,5, 6,6,6,6,6,6, 7,7,7,7,7,7};
    constexpr int SJ[42] = {2,3,4,5,6,7, 1,3,4,5,6,7, 1,2,4,5,6,7, 1,2,3,5,6,7,
                            1,2,3,4,6,7, 1,2,3,4,5,7, 1,2,3,4,5,6};
    constexpr int TG[42] = {4,5,2,3,7,6, 4,6,1,7,3,5, 5,6,7,1,2,4, 2,1,7,6,5,3,
                            3,7,1,6,4,2, 7,3,2,5,4,1, 6,5,4,3,2,1};
    constexpr float SG[42] = {+1,+1,+1,+1,+1,+1, -1,+1,-1,-1,+1,-1, -1,-1,+1,-1,-1,+1,
                              -1,+1,+1,-1,+1,-1, -1,-1,+1,+1,-1,+1, +1,-1,+1,-1,+1,-1,
                              +1,-1,+1,-1,+1,-1};
    int idx = blockIdx.x * 256 + threadIdx.x;        // B*T * 32 d-quads
    int dq = (idx & 31) * 4, bt = idx >> 5;
    size_t base = (size_t)bt * 1024 + dq;
    float4 o[8], r[8];
#pragma unroll
    for (int hh = 0; hh < 8; ++hh) {
        float4 a = *(const float4*)&out0[base + hh * 128];
        float4 b = *(const float4*)&out1[base + hh * 128];
        o[hh] = make_float4(a.x + b.x, a.y + b.y, a.z + b.z, a.w + b.w);
        r[hh] = o[hh];
    }
#pragma unroll
    for (int p = 0; p < 42; ++p) {
        float wgt = alpha[SI[p] * 8 + SJ[p]] * SG[p];
        r[TG[p]].x += wgt * o[SI[p]].x * o[SJ[p]].x;
        r[TG[p]].y += wgt * o[SI[p]].y * o[SJ[p]].y;
        r[TG[p]].z += wgt * o[SI[p]].z * o[SJ[p]].z;
        r[TG[p]].w += wgt * o[SI[p]].w * o[SJ[p]].w;
    }
#pragma unroll
    for (int hh = 0; hh < 8; ++hh) *(float4*)&fin[base + hh * 128] = r[hh];
}

// ---------------------------------------------------------------------------
extern "C" void kernel_launch(void* const* d_in, const int* in_sizes, int n_in,
                              void* d_out, int out_size, void* d_ws, size_t ws_size,
                              hipStream_t stream) {
    (void)in_sizes; (void)n_in; (void)out_size; (void)ws_size;
    const float* mv    = (const float*)d_in[0];
    const float* Wqkv  = (const float*)d_in[1];
    const float* Wo    = (const float*)d_in[2];
    const float* alpha = (const float*)d_in[3];
    float* outp = (float*)d_out;
    char* ws = (char*)d_ws;

    uint16_t* Xbf  = (uint16_t*)(ws + 0);            //  8 MB  [4096][1024]
    uint16_t* Wqt  = (uint16_t*)(ws + 8388608);      //  6 MB  [3072][1024]
    uint16_t* Wot  = (uint16_t*)(ws + 14680064);     //  2 MB  [1024][1024]
    uint16_t* Qr   = (uint16_t*)(ws + 41943040);     //  8 MB  [16][2048][128]
    uint16_t* Kr   = (uint16_t*)(ws + 50331648);     //  8 MB
    uint16_t* Vt   = (uint16_t*)(ws + 58720256);     //  8 MB  [16][128][2048]
    float*    ctab = (float*)(ws + 67108864);        // 0.5 MB
    float*    stab = (float*)(ws + 67633152);        // 0.5 MB
    uint16_t* AO   = (uint16_t*)(ws + 0);            // overlay (Xbf dead)
    float*    mlg  = (float*)(ws + 8388608);         // overlay (Wqt dead), 0.4 MB
    uint16_t* pbuf = (uint16_t*)(ws + 16777216);     // 12.6 MB partials
    float*    outF0 = (float*)(ws + 16777216);       // overlay (pbuf dead), 16 MB
    float*    outF1 = (float*)(ws + 33554432);       // 16 MB (Qr dead after attn)

    k_prep   <<<5632, 256, 0, stream>>>(mv, Wqkv, Wo, Xbf, Wqt, Wot, ctab, stab);
    k_gemmqkv<<<dim3(24, 32), 256, 0, stream>>>(Xbf, Wqt, ctab, stab, Qr, Kr, Vt);
    k_attn   <<<dim3(16, 48), 256, 0, stream>>>(Qr, Kr, Vt, pbuf, mlg, AO);
    k_amerge <<<dim3(16, 16), 256, 0, stream>>>(pbuf, mlg, AO);
    k_gemm2s <<<dim3(16, 32, 2), 256, 0, stream>>>(AO, Wot, outF0); // z=1 -> outF1
    k_mix    <<<512, 256, 0, stream>>>(outF0, outF1, alpha, outp);
}

// Round 20
// 116.229 us; speedup vs baseline: 2.0801x; 2.0801x over previous
//
#include <hip/hip_runtime.h>
#include <stdint.h>

// ---------------------------------------------------------------------------
// GeometricAttention: x@Wqkv (+fused RoPE/V-transpose epilogue) -> causal MHA
// (split-K chunks of 16 KV-tiles, single-buffered KV, 4 blocks/CU, + merge)
// -> @Wo (split-K) -> blade mixing (float4).
// B=2 T=2048 N=8 D=128, d_model=1024. bf16 MFMA pipeline, fp32 accum.
// FINAL configuration (R18): 115.9 us. R19's zero-barrier direct-global
// variant regressed 3.6x (uncoalesced per-lane fragment loads, MfmaUtil 3.9%)
// — LDS staging via global_load_lds IS the coalescing mechanism, reverted.
// ---------------------------------------------------------------------------

typedef __attribute__((ext_vector_type(8)))  __bf16 bf16x8;
typedef __attribute__((ext_vector_type(8)))  uint16_t u16x8;
typedef __attribute__((ext_vector_type(4)))  float  f32x4;

__device__ __forceinline__ uint16_t f2bf(float f) {
    uint32_t u = __float_as_uint(f);
    u += 0x7FFFu + ((u >> 16) & 1u);           // RNE
    return (uint16_t)(u >> 16);
}
__device__ __forceinline__ float bf2f(uint16_t h) {
    return __uint_as_float(((uint32_t)h) << 16);
}

__device__ __forceinline__ void gload_lds16(const void* g, void* l) {
    __builtin_amdgcn_global_load_lds(
        (__attribute__((address_space(1))) void*)g,
        (__attribute__((address_space(3))) void*)l, 16, 0, 0);
}

// ----------------------- fused prologue: cast / weight-transpose / rope tables
__global__ __launch_bounds__(256) void k_prep(const float* __restrict__ mv,
                                              const float* __restrict__ Wqkv,
                                              const float* __restrict__ Wo,
                                              uint16_t* __restrict__ Xbf,
                                              uint16_t* __restrict__ Wqt,
                                              uint16_t* __restrict__ Wot,
                                              float* __restrict__ ct,
                                              float* __restrict__ st) {
    __shared__ uint16_t tile[64][65];
    const int bid = blockIdx.x;
    const int tid = threadIdx.x;
    if (bid < 4096) {                                // cast
        int i = bid * 256 + tid;
        float4 v = ((const float4*)mv)[i];
        ((ushort4*)Xbf)[i] = make_ushort4(f2bf(v.x), f2bf(v.y), f2bf(v.z), f2bf(v.w));
    } else if (bid < 5120) {                         // weight transpose
        const float* W; uint16_t* Wt; int N, bx, by;
        if (bid < 4864) { W = Wqkv; Wt = Wqt; N = 3072;
                          int b2 = bid - 4096; bx = b2 % 48; by = b2 / 48; }
        else            { W = Wo;   Wt = Wot; N = 1024;
                          int b3 = bid - 4864; bx = b3 & 15; by = b3 >> 4; }
        const int k0 = by * 64, n0 = bx * 64;
        const int c = tid & 63, r4 = tid >> 6;
#pragma unroll
        for (int i = 0; i < 16; ++i) {
            int r = r4 + i * 4;
            tile[r][c] = f2bf(W[(size_t)(k0 + r) * N + n0 + c]);
        }
        __syncthreads();
#pragma unroll
        for (int i = 0; i < 16; ++i) {
            int r = r4 + i * 4;
            Wt[(size_t)(n0 + r) * 1024 + k0 + c] = tile[c][r];
        }
    } else {                                         // rope tables
        int i = (bid - 5120) * 256 + tid;            // 2048*64
        int t = i >> 6, f = i & 63;
        float inv = expf(-(float)f * 0.14391156830441f); // ln(10000)/64
        float ang = (float)t * inv;
        ct[i] = cosf(ang);
        st[i] = sinf(ang);
    }
}

// ---------------------- QKV GEMM (BK=64, swizzled LDS) + RoPE/V-T epilogue
__global__ __launch_bounds__(256) void k_gemmqkv(const uint16_t* __restrict__ A,
                                                 const uint16_t* __restrict__ Bt,
                                                 const float* __restrict__ ct,
                                                 const float* __restrict__ st,
                                                 uint16_t* __restrict__ Qr,
                                                 uint16_t* __restrict__ Kr,
                                                 uint16_t* __restrict__ Vt) {
    __shared__ __align__(16) char smem[33792];       // loop: 32KB A+B; epi: Tl
    uint16_t* Atile = (uint16_t*)smem;               // [128][64] swizzled
    uint16_t* Btile = (uint16_t*)(smem + 16384);     // [128][64] swizzled
    const int lin = blockIdx.y * 24 + blockIdx.x;
    const int logical = (lin & 7) * 96 + (lin >> 3); // XCD swizzle (bijective)
    const int bx = logical % 24;                     // n-tile 0..23
    const int m0 = (logical / 24) << 7, n0 = bx << 7;
    const int sec = bx >> 3, head = bx & 7;
    const int tid = threadIdx.x;
    const int l = tid & 63, w = tid >> 6;
    const int lr = l & 15, lg = l >> 4;
    const int wm = (w >> 1) << 6, wn = (w & 1) << 6;
    const int K = 1024;

    f32x4 acc[4][4];
#pragma unroll
    for (int i = 0; i < 4; ++i)
#pragma unroll
        for (int j = 0; j < 4; ++j) acc[i][j] = (f32x4){0.f, 0.f, 0.f, 0.f};

    for (int kt = 0; kt < 16; ++kt) {                // K = 16 x 64
        const int k0 = kt << 6;
        __syncthreads();
#pragma unroll
        for (int c = 0; c < 8; ++c) {                // 2048 16B chunks
            int idx = c * 256 + tid;
            if (idx < 1024) {                        // A: row r, chunk c16
                int r = idx >> 3, c16 = idx & 7;
                int sc = c16 ^ (r & 7);              // inverse swizzle on SOURCE
                gload_lds16(A + (size_t)(m0 + r) * K + k0 + sc * 8, Atile + idx * 8);
            } else {
                int i2 = idx - 1024;
                int r = i2 >> 3, c16 = i2 & 7;
                int sc = c16 ^ (r & 7);
                gload_lds16(Bt + (size_t)(n0 + r) * K + k0 + sc * 8, Btile + i2 * 8);
            }
        }
        __syncthreads();
#pragma unroll
        for (int kk = 0; kk < 2; ++kk) {
            bf16x8 af[4], bfv[4];
#pragma unroll
            for (int i = 0; i < 4; ++i) {
                int ra = wm + i * 16 + lr;
                af[i]  = *(const bf16x8*)((char*)Atile + ra * 128 +
                          ((kk * 64 + lg * 16) ^ ((ra & 7) << 4)));
                int rb = wn + i * 16 + lr;
                bfv[i] = *(const bf16x8*)((char*)Btile + rb * 128 +
                          ((kk * 64 + lg * 16) ^ ((rb & 7) << 4)));
            }
#pragma unroll
            for (int mi = 0; mi < 4; ++mi)
#pragma unroll
                for (int ni = 0; ni < 4; ++ni)
                    acc[mi][ni] = __builtin_amdgcn_mfma_f32_16x16x32_bf16(
                        af[mi], bfv[ni], acc[mi][ni], 0, 0, 0);
        }
    }

    // ---- epilogue: acc -> LDS bf16 tile (overlays Atile/Btile)
    __syncthreads();
    uint16_t (*Tl)[132] = (uint16_t(*)[132])smem;    // [128][132], 33792 B
#pragma unroll
    for (int mi = 0; mi < 4; ++mi)
#pragma unroll
        for (int ni = 0; ni < 4; ++ni)
#pragma unroll
            for (int r = 0; r < 4; ++r)
                Tl[wm + mi * 16 + lg * 4 + r][wn + ni * 16 + lr] =
                    f2bf(acc[mi][ni][r]);
    __syncthreads();

    const int b = m0 >> 11, t0 = m0 & 2047;
    const size_t hidx = (size_t)(b * 8 + head);
    if (sec < 2) {                                   // Q or K: rope + write
        uint16_t* outp = (sec == 0 ? Qr : Kr) + (hidx * 2048 + t0) * 128;
#pragma unroll
        for (int it = 0; it < 8; ++it) {
            int lin2 = it * 256 + tid;
            int tr = lin2 >> 4, d0 = (lin2 & 15) * 4;
            ushort4 lo = *(const ushort4*)&Tl[tr][d0];
            ushort4 hi = *(const ushort4*)&Tl[tr][d0 + 64];
            float4 cv = *(const float4*)&ct[(size_t)(t0 + tr) * 64 + d0];
            float4 sv = *(const float4*)&st[(size_t)(t0 + tr) * 64 + d0];
            ushort4 o1, o2;
            o1.x = f2bf(bf2f(lo.x) * cv.x - bf2f(hi.x) * sv.x);
            o2.x = f2bf(bf2f(hi.x) * cv.x + bf2f(lo.x) * sv.x);
            o1.y = f2bf(bf2f(lo.y) * cv.y - bf2f(hi.y) * sv.y);
            o2.y = f2bf(bf2f(hi.y) * cv.y + bf2f(lo.y) * sv.y);
            o1.z = f2bf(bf2f(lo.z) * cv.z - bf2f(hi.z) * sv.z);
            o2.z = f2bf(bf2f(hi.z) * cv.z + bf2f(lo.z) * sv.z);
            o1.w = f2bf(bf2f(lo.w) * cv.w - bf2f(hi.w) * sv.w);
            o2.w = f2bf(bf2f(hi.w) * cv.w + bf2f(lo.w) * sv.w);
            *(ushort4*)&outp[(size_t)tr * 128 + d0]      = o1;
            *(ushort4*)&outp[(size_t)tr * 128 + d0 + 64] = o2;
        }
    } else {                                         // V: transpose to [h][D][T]
        uint16_t* vp = Vt + hidx * 128 * 2048;
#pragma unroll
        for (int it = 0; it < 8; ++it) {
            int lin2 = it * 256 + tid;
            int d = lin2 >> 4, tq = (lin2 & 15) * 8;
            ushort4 v0 = make_ushort4(Tl[tq + 0][d], Tl[tq + 1][d],
                                      Tl[tq + 2][d], Tl[tq + 3][d]);
            ushort4 v1 = make_ushort4(Tl[tq + 4][d], Tl[tq + 5][d],
                                      Tl[tq + 6][d], Tl[tq + 7][d]);
            *(ushort4*)&vp[(size_t)d * 2048 + t0 + tq]     = v0;
            *(ushort4*)&vp[(size_t)d * 2048 + t0 + tq + 4] = v1;
        }
    }
}

// ------------------- split-K out-proj GEMM, 128x64 tiles, BK=64, swizzled
__global__ __launch_bounds__(256) void k_gemm2s(const uint16_t* __restrict__ A,
                                                const uint16_t* __restrict__ Bt,
                                                float* __restrict__ C) {
    __shared__ uint16_t Atile[128 * 64];             // 16 KB swizzled
    __shared__ uint16_t Btile[64 * 64];              //  8 KB swizzled
    const int kz = blockIdx.z;
    A  += (size_t)kz * 512;                          // k-offset within row
    Bt += (size_t)kz * 512;
    C  += (size_t)kz * (4096u * 1024u);              // partial-output buffer
    const int lin = blockIdx.y * 16 + blockIdx.x;
    const int logical = (lin & 7) * 64 + (lin >> 3); // XCD swizzle per z
    const int m0 = (logical >> 4) << 7, n0 = (logical & 15) << 6;
    const int tid = threadIdx.x;
    const int l = tid & 63, w = tid >> 6;
    const int lr = l & 15, lg = l >> 4;
    const int wm = (w >> 1) << 6, wn = (w & 1) << 5;

    f32x4 acc[4][2];
#pragma unroll
    for (int i = 0; i < 4; ++i)
#pragma unroll
        for (int j = 0; j < 2; ++j) acc[i][j] = (f32x4){0.f, 0.f, 0.f, 0.f};

    for (int kt = 0; kt < 8; ++kt) {                 // K_half = 512 = 8 x 64
        const int k0 = kt << 6;
        __syncthreads();
#pragma unroll
        for (int c = 0; c < 6; ++c) {                // 1536 16B chunks
            int idx = c * 256 + tid;
            if (idx < 1024) {                        // A: 128 rows x 8 chunks
                int r = idx >> 3, c16 = idx & 7;
                int sc = c16 ^ (r & 7);
                gload_lds16(A + (size_t)(m0 + r) * 1024 + k0 + sc * 8, Atile + idx * 8);
            } else {                                 // B: 64 rows x 8 chunks
                int i2 = idx - 1024;
                int r = i2 >> 3, c16 = i2 & 7;
                int sc = c16 ^ (r & 7);
                gload_lds16(Bt + (size_t)(n0 + r) * 1024 + k0 + sc * 8, Btile + i2 * 8);
            }
        }
        __syncthreads();
#pragma unroll
        for (int kk = 0; kk < 2; ++kk) {
            bf16x8 af[4], bfv[2];
#pragma unroll
            for (int i = 0; i < 4; ++i) {
                int ra = wm + i * 16 + lr;
                af[i] = *(const bf16x8*)((char*)Atile + ra * 128 +
                         ((kk * 64 + lg * 16) ^ ((ra & 7) << 4)));
            }
#pragma unroll
            for (int j = 0; j < 2; ++j) {
                int rb = wn + j * 16 + lr;
                bfv[j] = *(const bf16x8*)((char*)Btile + rb * 128 +
                          ((kk * 64 + lg * 16) ^ ((rb & 7) << 4)));
            }
#pragma unroll
            for (int mi = 0; mi < 4; ++mi)
#pragma unroll
                for (int ni = 0; ni < 2; ++ni)
                    acc[mi][ni] = __builtin_amdgcn_mfma_f32_16x16x32_bf16(
                        af[mi], bfv[ni], acc[mi][ni], 0, 0, 0);
        }
    }
#pragma unroll
    for (int mi = 0; mi < 4; ++mi)
#pragma unroll
        for (int ni = 0; ni < 2; ++ni)
#pragma unroll
            for (int r = 0; r < 4; ++r) {
                int row = m0 + wm + mi * 16 + lg * 4 + r;
                int col = n0 + wn + ni * 16 + lr;
                C[(size_t)row * 1024 + col] = acc[mi][ni][r];
            }
}

// --------------------------------------------------- causal flash attention
// R18 (final): split-K chunks of 16 KV-tiles, single-buffered KVBLK=64 at
// 40KB LDS = 4 blocks/CU. Grid (16,48) = 768 blocks, heavy chunks first.
// qt<=15 (single chunk) writes AO directly; qt>=16 has exactly 2 chunks.
// Decode: y<32 -> qt=31-(y>>1), ci=y&1; else qt=47-y, ci=0.
__global__ __launch_bounds__(256) void k_attn(const uint16_t* __restrict__ Qg,
                                              const uint16_t* __restrict__ Kg,
                                              const uint16_t* __restrict__ Vtg,
                                              uint16_t* __restrict__ pbuf,
                                              float* __restrict__ mlg,
                                              uint16_t* __restrict__ AOg) {
    __shared__ uint16_t Klds[64 * 128];              // 16 KB, XOR-swizzled
    __shared__ uint16_t Vlds[128 * 64];              // 16 KB, XOR-swizzled
    __shared__ uint16_t Plds[4][16 * 64];            //  8 KB, per-wave

    const int h = blockIdx.x;
    const int y = blockIdx.y;                        // 0..47
    const int qt = (y < 32) ? (31 - (y >> 1)) : (47 - y);
    const int ci = (y < 32) ? (y & 1) : 0;
    const int slot = h * 48 + y;
    const int p0 = ci * 16;
    const int pend = min(p0 + 16, qt + 1);
    const int q0 = qt * 64;
    const int tid = threadIdx.x;
    const int l = tid & 63, w = tid >> 6;
    const int lr = l & 15, lg = l >> 4;
    const size_t headTD = (size_t)h * (2048 * 128);
    const uint16_t* Kh = Kg + headTD;
    const uint16_t* Vh = Vtg + headTD;

    bf16x8 qf[4];
    {
        const uint16_t* qp = Qg + headTD + (size_t)(q0 + w * 16 + lr) * 128 + lg * 8;
#pragma unroll
        for (int kc = 0; kc < 4; ++kc) qf[kc] = *(const bf16x8*)(qp + kc * 32);
    }

    f32x4 accO[8];
#pragma unroll
    for (int i = 0; i < 8; ++i) accO[i] = (f32x4){0.f, 0.f, 0.f, 0.f};
    float mrun = -1e30f, lrun = 0.f;                 // per-lane row q = lr

    const float SL2E = 0.08838834764831845f * 1.4426950408889634f; // scale*log2e
    const int   swz  = (lr & 7) << 4;                // per-lane swizzle (row=lr)
    uint16_t* Pw = &Plds[w][0];

    auto STAGE = [&](int k0) {
#pragma unroll
        for (int p = 0; p < 4; ++p) {                // K: 64x128 rows of 256B
            int u = p * 256 + tid;                   // 16B chunk id
            int row = u >> 4;
            int c16 = (u & 15) ^ (row & 7);          // inverse swizzle on SOURCE
            gload_lds16(Kh + (size_t)(k0 + row) * 128 + c16 * 8,
                        (char*)&Klds[0] + u * 16);
        }
#pragma unroll
        for (int p = 0; p < 4; ++p) {                // V: 128x64 rows of 128B
            int u = p * 256 + tid;
            int d = u >> 3;
            int c8 = (u & 7) ^ (d & 7);
            gload_lds16(Vh + (size_t)d * 2048 + k0 + c8 * 8,
                        (char*)&Vlds[0] + u * 16);
        }
    };

    for (int kt = p0; kt < pend; ++kt) {
        STAGE(kt * 64);                              // single buffer
        asm volatile("s_waitcnt vmcnt(0)" ::: "memory");
        __builtin_amdgcn_s_barrier();                // tile loaded (all waves)
        __builtin_amdgcn_sched_barrier(0);

        const char* Kb = (const char*)&Klds[0];
        const char* Vb = (const char*)&Vlds[0];

        // ---- S^T = K Q^T : lane holds S[q=lr][k = cg*16 + lg*4 + r] ------
        float sv[4][4];
        __builtin_amdgcn_s_setprio(1);
#pragma unroll
        for (int cg = 0; cg < 4; ++cg) {
            f32x4 a = (f32x4){0.f, 0.f, 0.f, 0.f};
#pragma unroll
            for (int kc = 0; kc < 4; ++kc) {
                int kb = (cg * 16 + lr) * 256 + ((kc * 64 + lg * 16) ^ swz);
                bf16x8 kf = *(const bf16x8*)(Kb + kb);
                a = __builtin_amdgcn_mfma_f32_16x16x32_bf16(kf, qf[kc], a, 0, 0, 0);
            }
#pragma unroll
            for (int r = 0; r < 4; ++r) sv[cg][r] = a[r];
        }
        __builtin_amdgcn_s_setprio(0);

        if (kt == qt) {                              // causal mask, diagonal tile
#pragma unroll
            for (int cg = 0; cg < 4; ++cg)
#pragma unroll
                for (int r = 0; r < 4; ++r)
                    if (cg * 16 + lg * 4 + r > w * 16 + lr) sv[cg][r] = -1e30f;
        }

        // ---- defer-max online softmax (lane-local row) -------------------
        float pml = sv[0][0];
#pragma unroll
        for (int cg = 0; cg < 4; ++cg)
#pragma unroll
            for (int r = 0; r < 4; ++r) pml = fmaxf(pml, sv[cg][r]);

        if (!__all(pml * SL2E <= mrun + 11.f)) {     // rare: true max + rescale
            float mx = pml;
            mx = fmaxf(mx, __shfl_xor(mx, 16, 64));
            mx = fmaxf(mx, __shfl_xor(mx, 32, 64));  // full row max (q = lr)
            float mn = fmaxf(mrun, mx * SL2E);
            float corr = exp2f(mrun - mn);
            mrun = mn;
            lrun *= corr;                            // lane-partial sum scales too
            float ca[4];
#pragma unroll
            for (int r = 0; r < 4; ++r)              // corr for accO rows q=lg*4+r
                ca[r] = __shfl(corr, (lg << 4) + lg * 4 + r, 64);
#pragma unroll
            for (int i = 0; i < 8; ++i)
#pragma unroll
                for (int r = 0; r < 4; ++r) accO[i][r] *= ca[r];
        }

        float psum = 0.f;
        float p[4][4];
#pragma unroll
        for (int cg = 0; cg < 4; ++cg)
#pragma unroll
            for (int r = 0; r < 4; ++r) {
                p[cg][r] = exp2f(fmaf(sv[cg][r], SL2E, -mrun));
                psum += p[cg][r];
            }
        lrun += psum;

        // pack P pairs -> b64 LDS writes (row q=lr, k = 16cg+4lg .. +3)
#pragma unroll
        for (int cg = 0; cg < 4; ++cg) {
            uint32_t w0, w1;
            asm("v_cvt_pk_bf16_f32 %0, %1, %2" : "=v"(w0) : "v"(p[cg][0]), "v"(p[cg][1]));
            asm("v_cvt_pk_bf16_f32 %0, %1, %2" : "=v"(w1) : "v"(p[cg][2]), "v"(p[cg][3]));
            uint2 pr; pr.x = w0; pr.y = w1;
            *(uint2*)((char*)Pw + lr * 128 + ((cg * 32 + lg * 8) ^ swz)) = pr;
        }

        asm volatile("" ::: "memory");               // order P stores before reads
        bf16x8 pf[2];
#pragma unroll
        for (int c = 0; c < 2; ++c)
            pf[c] = *(const bf16x8*)((char*)Pw + lr * 128 + ((c * 64 + lg * 16) ^ swz));

        __builtin_amdgcn_s_setprio(1);
#pragma unroll
        for (int ni = 0; ni < 8; ++ni)
#pragma unroll
            for (int c = 0; c < 2; ++c) {
                int vb = (ni * 16 + lr) * 128 + ((c * 64 + lg * 16) ^ swz);
                bf16x8 vf = *(const bf16x8*)(Vb + vb);
                accO[ni] = __builtin_amdgcn_mfma_f32_16x16x32_bf16(pf[c], vf, accO[ni], 0, 0, 0);
            }
        __builtin_amdgcn_s_setprio(0);

        __builtin_amdgcn_s_barrier();                // all reads done before next STAGE
    }

    // ---- epilogue ---------------------------------------------------------
    float lsum = lrun;
    lsum += __shfl_xor(lsum, 16, 64);
    lsum += __shfl_xor(lsum, 32, 64);                // full sum for row q = lr

    if (qt <= 15) {                                  // single chunk: direct AO
        float linv = 1.f / lsum;
        float inv[4];
#pragma unroll
        for (int r = 0; r < 4; ++r)
            inv[r] = __shfl(linv, (lg << 4) + lg * 4 + r, 64);
        const int b = h >> 3, n = h & 7;
#pragma unroll
        for (int ni = 0; ni < 8; ++ni)
#pragma unroll
            for (int r = 0; r < 4; ++r) {
                int trow = q0 + w * 16 + lg * 4 + r;
                AOg[((size_t)(b * 2048 + trow)) * 1024 + n * 128 + ni * 16 + lr] =
                    f2bf(accO[ni][r] * inv[r]);
            }
    } else {                                         // partial + (m, l)
        uint16_t* pb = pbuf + (size_t)slot * 8192;
#pragma unroll
        for (int ni = 0; ni < 8; ++ni)
#pragma unroll
            for (int r = 0; r < 4; ++r) {
                int row = w * 16 + lg * 4 + r;
                pb[row * 128 + ni * 16 + lr] = f2bf(accO[ni][r]);
            }
        if (lg == 0) {                               // one lane per (w,lr) row
            mlg[slot * 128 + w * 16 + lr]      = mrun;   // scaled-log2 domain
            mlg[slot * 128 + 64 + w * 16 + lr] = lsum;
        }
    }
}

// ------------------------------- split-K partial merge -> AO (qt >= 16, nc=2)
__global__ __launch_bounds__(256) void k_amerge(const uint16_t* __restrict__ pbuf,
                                                const float* __restrict__ mlg,
                                                uint16_t* __restrict__ AOg) {
    const int h = blockIdx.x, qt = 16 + blockIdx.y;  // qt in [16, 31]
    const int slot0 = h * 48 + 2 * (31 - qt);        // y = 2*(31-qt), +1
    const int tid = threadIdx.x;
    const int row = tid >> 2, dq = (tid & 3) * 32;

    float m0 = mlg[slot0 * 128 + row];
    float m1 = mlg[(slot0 + 1) * 128 + row];
    float M  = fmaxf(m0, m1);
    float w0 = exp2f(m0 - M), w1 = exp2f(m1 - M);
    float L  = mlg[slot0 * 128 + 64 + row] * w0 +
               mlg[(slot0 + 1) * 128 + 64 + row] * w1;
    float inv = 1.f / L;
    w0 *= inv; w1 *= inv;

    const u16x8* p0 = (const u16x8*)(pbuf + (size_t)slot0 * 8192 + row * 128 + dq);
    const u16x8* p1 = (const u16x8*)(pbuf + (size_t)(slot0 + 1) * 8192 + row * 128 + dq);
    const int b = h >> 3, n = h & 7;
    uint16_t* op = AOg + ((size_t)(b * 2048 + qt * 64 + row)) * 1024 + n * 128 + dq;
#pragma unroll
    for (int jj = 0; jj < 4; ++jj) {
        u16x8 a = p0[jj], c = p1[jj], v;
#pragma unroll
        for (int k = 0; k < 8; ++k)
            v[k] = f2bf(bf2f(a[k]) * w0 + bf2f(c[k]) * w1);
        ((u16x8*)op)[jj] = v;
    }
}

// ------------------------------- blade mixing epilogue (float4 + split-K add)
__global__ __launch_bounds__(256) void k_mix(const float* __restrict__ out0,
                                             const float* __restrict__ out1,
                                             const float* __restrict__ alpha,
                                             float* __restrict__ fin) {
    constexpr int SI[42] = {1,1,1,1,1,1, 2,2,2,2,2,2, 3,3,3,3,3,3, 4,4,4,4,4,4,
                            5,5,5,5,5,5, 6,6,6,6,6,6, 7,7,7,7,7,7};
    constexpr int SJ[42] = {2,3,4,5,6,7, 1,3,4,5,6,7, 1,2,4,5,6,7, 1,2,3,5,6,7,
                            1,2,3,4,6,7, 1,2,3,4,5,7, 1,2,3,4,5,6};
    constexpr int TG[42] = {4,5,2,3,7,6, 4,6,1,7,3,5, 5,6,7,1,2,4, 2,1,7,6,5,3,
                            3,7,1,6,4,2, 7,3,2,5,4,1, 6,5,4,3,2,1};
    constexpr float SG[42] = {+1,+1,+1,+1,+1,+1, -1,+1,-1,-1,+1,-1, -1,-1,+1,-1,-1,+1,
                              -1,+1,+1,-1,+1,-1, -1,-1,+1,+1,-1,+1, +1,-1,+1,-1,+1,-1,
                              +1,-1,+1,-1,+1,-1};
    int idx = blockIdx.x * 256 + threadIdx.x;        // B*T * 32 d-quads
    int dq = (idx & 31) * 4, bt = idx >> 5;
    size_t base = (size_t)bt * 1024 + dq;
    float4 o[8], r[8];
#pragma unroll
    for (int hh = 0; hh < 8; ++hh) {
        float4 a = *(const float4*)&out0[base + hh * 128];
        float4 b = *(const float4*)&out1[base + hh * 128];
        o[hh] = make_float4(a.x + b.x, a.y + b.y, a.z + b.z, a.w + b.w);
        r[hh] = o[hh];
    }
#pragma unroll
    for (int p = 0; p < 42; ++p) {
        float wgt = alpha[SI[p] * 8 + SJ[p]] * SG[p];
        r[TG[p]].x += wgt * o[SI[p]].x * o[SJ[p]].x;
        r[TG[p]].y += wgt * o[SI[p]].y * o[SJ[p]].y;
        r[TG[p]].z += wgt * o[SI[p]].z * o[SJ[p]].z;
        r[TG[p]].w += wgt * o[SI[p]].w * o[SJ[p]].w;
    }
#pragma unroll
    for (int hh = 0; hh < 8; ++hh) *(float4*)&fin[base + hh * 128] = r[hh];
}

// ---------------------------------------------------------------------------
extern "C" void kernel_launch(void* const* d_in, const int* in_sizes, int n_in,
                              void* d_out, int out_size, void* d_ws, size_t ws_size,
                              hipStream_t stream) {
    (void)in_sizes; (void)n_in; (void)out_size; (void)ws_size;
    const float* mv    = (const float*)d_in[0];
    const float* Wqkv  = (const float*)d_in[1];
    const float* Wo    = (const float*)d_in[2];
    const float* alpha = (const float*)d_in[3];
    float* outp = (float*)d_out;
    char* ws = (char*)d_ws;

    uint16_t* Xbf  = (uint16_t*)(ws + 0);            //  8 MB  [4096][1024]
    uint16_t* Wqt  = (uint16_t*)(ws + 8388608);      //  6 MB  [3072][1024]
    uint16_t* Wot  = (uint16_t*)(ws + 14680064);     //  2 MB  [1024][1024]
    uint16_t* Qr   = (uint16_t*)(ws + 41943040);     //  8 MB  [16][2048][128]
    uint16_t* Kr   = (uint16_t*)(ws + 50331648);     //  8 MB
    uint16_t* Vt   = (uint16_t*)(ws + 58720256);     //  8 MB  [16][128][2048]
    float*    ctab = (float*)(ws + 67108864);        // 0.5 MB
    float*    stab = (float*)(ws + 67633152);        // 0.5 MB
    uint16_t* AO   = (uint16_t*)(ws + 0);            // overlay (Xbf dead)
    float*    mlg  = (float*)(ws + 8388608);         // overlay (Wqt dead), 0.4 MB
    uint16_t* pbuf = (uint16_t*)(ws + 16777216);     // 12.6 MB partials
    float*    outF0 = (float*)(ws + 16777216);       // overlay (pbuf dead), 16 MB
    float*    outF1 = (float*)(ws + 33554432);       // 16 MB (Qr dead after attn)

    k_prep   <<<5632, 256, 0, stream>>>(mv, Wqkv, Wo, Xbf, Wqt, Wot, ctab, stab);
    k_gemmqkv<<<dim3(24, 32), 256, 0, stream>>>(Xbf, Wqt, ctab, stab, Qr, Kr, Vt);
    k_attn   <<<dim3(16, 48), 256, 0, stream>>>(Qr, Kr, Vt, pbuf, mlg, AO);
    k_amerge <<<dim3(16, 16), 256, 0, stream>>>(pbuf, mlg, AO);
    k_gemm2s <<<dim3(16, 32, 2), 256, 0, stream>>>(AO, Wot, outF0); // z=1 -> outF1
    k_mix    <<<512, 256, 0, stream>>>(outF0, outF1, alpha, outp);
}

// Round 21
// 112.762 us; speedup vs baseline: 2.1440x; 1.0307x over previous
//
#include <hip/hip_runtime.h>
#include <stdint.h>

// ---------------------------------------------------------------------------
// GeometricAttention: x@Wqkv (+fused RoPE/V-transpose epilogue) -> causal MHA
// (split-K chunks of 16 KV-tiles, single-buffered KV, 4 blocks/CU, + merge)
// -> @Wo (split-K, bf16 partials) -> blade mixing (ushort4 loads).
// B=2 T=2048 N=8 D=128, d_model=1024. bf16 MFMA pipeline, fp32 accum.
// ---------------------------------------------------------------------------

typedef __attribute__((ext_vector_type(8)))  __bf16 bf16x8;
typedef __attribute__((ext_vector_type(8)))  uint16_t u16x8;
typedef __attribute__((ext_vector_type(4)))  float  f32x4;

__device__ __forceinline__ uint16_t f2bf(float f) {
    uint32_t u = __float_as_uint(f);
    u += 0x7FFFu + ((u >> 16) & 1u);           // RNE
    return (uint16_t)(u >> 16);
}
__device__ __forceinline__ float bf2f(uint16_t h) {
    return __uint_as_float(((uint32_t)h) << 16);
}

__device__ __forceinline__ void gload_lds16(const void* g, void* l) {
    __builtin_amdgcn_global_load_lds(
        (__attribute__((address_space(1))) void*)g,
        (__attribute__((address_space(3))) void*)l, 16, 0, 0);
}

// ----------------------- fused prologue: cast / weight-transpose / rope tables
__global__ __launch_bounds__(256) void k_prep(const float* __restrict__ mv,
                                              const float* __restrict__ Wqkv,
                                              const float* __restrict__ Wo,
                                              uint16_t* __restrict__ Xbf,
                                              uint16_t* __restrict__ Wqt,
                                              uint16_t* __restrict__ Wot,
                                              float* __restrict__ ct,
                                              float* __restrict__ st) {
    __shared__ uint16_t tile[64][65];
    const int bid = blockIdx.x;
    const int tid = threadIdx.x;
    if (bid < 4096) {                                // cast
        int i = bid * 256 + tid;
        float4 v = ((const float4*)mv)[i];
        ((ushort4*)Xbf)[i] = make_ushort4(f2bf(v.x), f2bf(v.y), f2bf(v.z), f2bf(v.w));
    } else if (bid < 5120) {                         // weight transpose
        const float* W; uint16_t* Wt; int N, bx, by;
        if (bid < 4864) { W = Wqkv; Wt = Wqt; N = 3072;
                          int b2 = bid - 4096; bx = b2 % 48; by = b2 / 48; }
        else            { W = Wo;   Wt = Wot; N = 1024;
                          int b3 = bid - 4864; bx = b3 & 15; by = b3 >> 4; }
        const int k0 = by * 64, n0 = bx * 64;
        const int c = tid & 63, r4 = tid >> 6;
#pragma unroll
        for (int i = 0; i < 16; ++i) {
            int r = r4 + i * 4;
            tile[r][c] = f2bf(W[(size_t)(k0 + r) * N + n0 + c]);
        }
        __syncthreads();
#pragma unroll
        for (int i = 0; i < 16; ++i) {
            int r = r4 + i * 4;
            Wt[(size_t)(n0 + r) * 1024 + k0 + c] = tile[c][r];
        }
    } else {                                         // rope tables
        int i = (bid - 5120) * 256 + tid;            // 2048*64
        int t = i >> 6, f = i & 63;
        float inv = expf(-(float)f * 0.14391156830441f); // ln(10000)/64
        float ang = (float)t * inv;
        ct[i] = cosf(ang);
        st[i] = sinf(ang);
    }
}

// ---------------------- QKV GEMM (BK=64, swizzled LDS) + RoPE/V-T epilogue
__global__ __launch_bounds__(256) void k_gemmqkv(const uint16_t* __restrict__ A,
                                                 const uint16_t* __restrict__ Bt,
                                                 const float* __restrict__ ct,
                                                 const float* __restrict__ st,
                                                 uint16_t* __restrict__ Qr,
                                                 uint16_t* __restrict__ Kr,
                                                 uint16_t* __restrict__ Vt) {
    __shared__ __align__(16) char smem[33792];       // loop: 32KB A+B; epi: Tl
    uint16_t* Atile = (uint16_t*)smem;               // [128][64] swizzled
    uint16_t* Btile = (uint16_t*)(smem + 16384);     // [128][64] swizzled
    const int lin = blockIdx.y * 24 + blockIdx.x;
    const int logical = (lin & 7) * 96 + (lin >> 3); // XCD swizzle (bijective)
    const int bx = logical % 24;                     // n-tile 0..23
    const int m0 = (logical / 24) << 7, n0 = bx << 7;
    const int sec = bx >> 3, head = bx & 7;
    const int tid = threadIdx.x;
    const int l = tid & 63, w = tid >> 6;
    const int lr = l & 15, lg = l >> 4;
    const int wm = (w >> 1) << 6, wn = (w & 1) << 6;
    const int K = 1024;

    f32x4 acc[4][4];
#pragma unroll
    for (int i = 0; i < 4; ++i)
#pragma unroll
        for (int j = 0; j < 4; ++j) acc[i][j] = (f32x4){0.f, 0.f, 0.f, 0.f};

    for (int kt = 0; kt < 16; ++kt) {                // K = 16 x 64
        const int k0 = kt << 6;
        __syncthreads();
#pragma unroll
        for (int c = 0; c < 8; ++c) {                // 2048 16B chunks
            int idx = c * 256 + tid;
            if (idx < 1024) {                        // A: row r, chunk c16
                int r = idx >> 3, c16 = idx & 7;
                int sc = c16 ^ (r & 7);              // inverse swizzle on SOURCE
                gload_lds16(A + (size_t)(m0 + r) * K + k0 + sc * 8, Atile + idx * 8);
            } else {
                int i2 = idx - 1024;
                int r = i2 >> 3, c16 = i2 & 7;
                int sc = c16 ^ (r & 7);
                gload_lds16(Bt + (size_t)(n0 + r) * K + k0 + sc * 8, Btile + i2 * 8);
            }
        }
        __syncthreads();
#pragma unroll
        for (int kk = 0; kk < 2; ++kk) {
            bf16x8 af[4], bfv[4];
#pragma unroll
            for (int i = 0; i < 4; ++i) {
                int ra = wm + i * 16 + lr;
                af[i]  = *(const bf16x8*)((char*)Atile + ra * 128 +
                          ((kk * 64 + lg * 16) ^ ((ra & 7) << 4)));
                int rb = wn + i * 16 + lr;
                bfv[i] = *(const bf16x8*)((char*)Btile + rb * 128 +
                          ((kk * 64 + lg * 16) ^ ((rb & 7) << 4)));
            }
#pragma unroll
            for (int mi = 0; mi < 4; ++mi)
#pragma unroll
                for (int ni = 0; ni < 4; ++ni)
                    acc[mi][ni] = __builtin_amdgcn_mfma_f32_16x16x32_bf16(
                        af[mi], bfv[ni], acc[mi][ni], 0, 0, 0);
        }
    }

    // ---- epilogue: acc -> LDS bf16 tile (overlays Atile/Btile)
    __syncthreads();
    uint16_t (*Tl)[132] = (uint16_t(*)[132])smem;    // [128][132], 33792 B
#pragma unroll
    for (int mi = 0; mi < 4; ++mi)
#pragma unroll
        for (int ni = 0; ni < 4; ++ni)
#pragma unroll
            for (int r = 0; r < 4; ++r)
                Tl[wm + mi * 16 + lg * 4 + r][wn + ni * 16 + lr] =
                    f2bf(acc[mi][ni][r]);
    __syncthreads();

    const int b = m0 >> 11, t0 = m0 & 2047;
    const size_t hidx = (size_t)(b * 8 + head);
    if (sec < 2) {                                   // Q or K: rope + write
        uint16_t* outp = (sec == 0 ? Qr : Kr) + (hidx * 2048 + t0) * 128;
#pragma unroll
        for (int it = 0; it < 8; ++it) {
            int lin2 = it * 256 + tid;
            int tr = lin2 >> 4, d0 = (lin2 & 15) * 4;
            ushort4 lo = *(const ushort4*)&Tl[tr][d0];
            ushort4 hi = *(const ushort4*)&Tl[tr][d0 + 64];
            float4 cv = *(const float4*)&ct[(size_t)(t0 + tr) * 64 + d0];
            float4 sv = *(const float4*)&st[(size_t)(t0 + tr) * 64 + d0];
            ushort4 o1, o2;
            o1.x = f2bf(bf2f(lo.x) * cv.x - bf2f(hi.x) * sv.x);
            o2.x = f2bf(bf2f(hi.x) * cv.x + bf2f(lo.x) * sv.x);
            o1.y = f2bf(bf2f(lo.y) * cv.y - bf2f(hi.y) * sv.y);
            o2.y = f2bf(bf2f(hi.y) * cv.y + bf2f(lo.y) * sv.y);
            o1.z = f2bf(bf2f(lo.z) * cv.z - bf2f(hi.z) * sv.z);
            o2.z = f2bf(bf2f(hi.z) * cv.z + bf2f(lo.z) * sv.z);
            o1.w = f2bf(bf2f(lo.w) * cv.w - bf2f(hi.w) * sv.w);
            o2.w = f2bf(bf2f(hi.w) * cv.w + bf2f(lo.w) * sv.w);
            *(ushort4*)&outp[(size_t)tr * 128 + d0]      = o1;
            *(ushort4*)&outp[(size_t)tr * 128 + d0 + 64] = o2;
        }
    } else {                                         // V: transpose to [h][D][T]
        uint16_t* vp = Vt + hidx * 128 * 2048;
#pragma unroll
        for (int it = 0; it < 8; ++it) {
            int lin2 = it * 256 + tid;
            int d = lin2 >> 4, tq = (lin2 & 15) * 8;
            ushort4 v0 = make_ushort4(Tl[tq + 0][d], Tl[tq + 1][d],
                                      Tl[tq + 2][d], Tl[tq + 3][d]);
            ushort4 v1 = make_ushort4(Tl[tq + 4][d], Tl[tq + 5][d],
                                      Tl[tq + 6][d], Tl[tq + 7][d]);
            *(ushort4*)&vp[(size_t)d * 2048 + t0 + tq]     = v0;
            *(ushort4*)&vp[(size_t)d * 2048 + t0 + tq + 4] = v1;
        }
    }
}

// ------- split-K out-proj GEMM, 128x64 tiles, BK=64, swizzled, BF16 partials
// Halves write bf16 partial C (8 MB each, was 16 MB f32) -> k_mix sums.
// Error budget: half-sums ~N(0,0.5); bf16 RNE adds ~1.4e-3/half -> ~3e-3 on
// out, <=6e-3 after quadratic mixing; measured absmax 0.0156 vs thr 0.0706.
__global__ __launch_bounds__(256) void k_gemm2s(const uint16_t* __restrict__ A,
                                                const uint16_t* __restrict__ Bt,
                                                uint16_t* __restrict__ C) {
    __shared__ uint16_t Atile[128 * 64];             // 16 KB swizzled
    __shared__ uint16_t Btile[64 * 64];              //  8 KB swizzled
    const int kz = blockIdx.z;
    A  += (size_t)kz * 512;                          // k-offset within row
    Bt += (size_t)kz * 512;
    C  += (size_t)kz * (4096u * 1024u);              // bf16 partial buffer
    const int lin = blockIdx.y * 16 + blockIdx.x;
    const int logical = (lin & 7) * 64 + (lin >> 3); // XCD swizzle per z
    const int m0 = (logical >> 4) << 7, n0 = (logical & 15) << 6;
    const int tid = threadIdx.x;
    const int l = tid & 63, w = tid >> 6;
    const int lr = l & 15, lg = l >> 4;
    const int wm = (w >> 1) << 6, wn = (w & 1) << 5;

    f32x4 acc[4][2];
#pragma unroll
    for (int i = 0; i < 4; ++i)
#pragma unroll
        for (int j = 0; j < 2; ++j) acc[i][j] = (f32x4){0.f, 0.f, 0.f, 0.f};

    for (int kt = 0; kt < 8; ++kt) {                 // K_half = 512 = 8 x 64
        const int k0 = kt << 6;
        __syncthreads();
#pragma unroll
        for (int c = 0; c < 6; ++c) {                // 1536 16B chunks
            int idx = c * 256 + tid;
            if (idx < 1024) {                        // A: 128 rows x 8 chunks
                int r = idx >> 3, c16 = idx & 7;
                int sc = c16 ^ (r & 7);
                gload_lds16(A + (size_t)(m0 + r) * 1024 + k0 + sc * 8, Atile + idx * 8);
            } else {                                 // B: 64 rows x 8 chunks
                int i2 = idx - 1024;
                int r = i2 >> 3, c16 = i2 & 7;
                int sc = c16 ^ (r & 7);
                gload_lds16(Bt + (size_t)(n0 + r) * 1024 + k0 + sc * 8, Btile + i2 * 8);
            }
        }
        __syncthreads();
#pragma unroll
        for (int kk = 0; kk < 2; ++kk) {
            bf16x8 af[4], bfv[2];
#pragma unroll
            for (int i = 0; i < 4; ++i) {
                int ra = wm + i * 16 + lr;
                af[i] = *(const bf16x8*)((char*)Atile + ra * 128 +
                         ((kk * 64 + lg * 16) ^ ((ra & 7) << 4)));
            }
#pragma unroll
            for (int j = 0; j < 2; ++j) {
                int rb = wn + j * 16 + lr;
                bfv[j] = *(const bf16x8*)((char*)Btile + rb * 128 +
                          ((kk * 64 + lg * 16) ^ ((rb & 7) << 4)));
            }
#pragma unroll
            for (int mi = 0; mi < 4; ++mi)
#pragma unroll
                for (int ni = 0; ni < 2; ++ni)
                    acc[mi][ni] = __builtin_amdgcn_mfma_f32_16x16x32_bf16(
                        af[mi], bfv[ni], acc[mi][ni], 0, 0, 0);
        }
    }
#pragma unroll
    for (int mi = 0; mi < 4; ++mi)
#pragma unroll
        for (int ni = 0; ni < 2; ++ni)
#pragma unroll
            for (int r = 0; r < 4; ++r) {
                int row = m0 + wm + mi * 16 + lg * 4 + r;
                int col = n0 + wn + ni * 16 + lr;
                C[(size_t)row * 1024 + col] = f2bf(acc[mi][ni][r]);
            }
}

// --------------------------------------------------- causal flash attention
// R18 (final attention): split-K chunks of 16 KV-tiles, single-buffered
// KVBLK=64 at 40KB LDS = 4 blocks/CU. Grid (16,48) = 768 blocks, heavy first.
// qt<=15 writes AO directly; qt>=16 has exactly 2 chunks (nc=2 merge).
__global__ __launch_bounds__(256) void k_attn(const uint16_t* __restrict__ Qg,
                                              const uint16_t* __restrict__ Kg,
                                              const uint16_t* __restrict__ Vtg,
                                              uint16_t* __restrict__ pbuf,
                                              float* __restrict__ mlg,
                                              uint16_t* __restrict__ AOg) {
    __shared__ uint16_t Klds[64 * 128];              // 16 KB, XOR-swizzled
    __shared__ uint16_t Vlds[128 * 64];              // 16 KB, XOR-swizzled
    __shared__ uint16_t Plds[4][16 * 64];            //  8 KB, per-wave

    const int h = blockIdx.x;
    const int y = blockIdx.y;                        // 0..47
    const int qt = (y < 32) ? (31 - (y >> 1)) : (47 - y);
    const int ci = (y < 32) ? (y & 1) : 0;
    const int slot = h * 48 + y;
    const int p0 = ci * 16;
    const int pend = min(p0 + 16, qt + 1);
    const int q0 = qt * 64;
    const int tid = threadIdx.x;
    const int l = tid & 63, w = tid >> 6;
    const int lr = l & 15, lg = l >> 4;
    const size_t headTD = (size_t)h * (2048 * 128);
    const uint16_t* Kh = Kg + headTD;
    const uint16_t* Vh = Vtg + headTD;

    bf16x8 qf[4];
    {
        const uint16_t* qp = Qg + headTD + (size_t)(q0 + w * 16 + lr) * 128 + lg * 8;
#pragma unroll
        for (int kc = 0; kc < 4; ++kc) qf[kc] = *(const bf16x8*)(qp + kc * 32);
    }

    f32x4 accO[8];
#pragma unroll
    for (int i = 0; i < 8; ++i) accO[i] = (f32x4){0.f, 0.f, 0.f, 0.f};
    float mrun = -1e30f, lrun = 0.f;                 // per-lane row q = lr

    const float SL2E = 0.08838834764831845f * 1.4426950408889634f; // scale*log2e
    const int   swz  = (lr & 7) << 4;                // per-lane swizzle (row=lr)
    uint16_t* Pw = &Plds[w][0];

    auto STAGE = [&](int k0) {
#pragma unroll
        for (int p = 0; p < 4; ++p) {                // K: 64x128 rows of 256B
            int u = p * 256 + tid;                   // 16B chunk id
            int row = u >> 4;
            int c16 = (u & 15) ^ (row & 7);          // inverse swizzle on SOURCE
            gload_lds16(Kh + (size_t)(k0 + row) * 128 + c16 * 8,
                        (char*)&Klds[0] + u * 16);
        }
#pragma unroll
        for (int p = 0; p < 4; ++p) {                // V: 128x64 rows of 128B
            int u = p * 256 + tid;
            int d = u >> 3;
            int c8 = (u & 7) ^ (d & 7);
            gload_lds16(Vh + (size_t)d * 2048 + k0 + c8 * 8,
                        (char*)&Vlds[0] + u * 16);
        }
    };

    for (int kt = p0; kt < pend; ++kt) {
        STAGE(kt * 64);                              // single buffer
        asm volatile("s_waitcnt vmcnt(0)" ::: "memory");
        __builtin_amdgcn_s_barrier();                // tile loaded (all waves)
        __builtin_amdgcn_sched_barrier(0);

        const char* Kb = (const char*)&Klds[0];
        const char* Vb = (const char*)&Vlds[0];

        // ---- S^T = K Q^T : lane holds S[q=lr][k = cg*16 + lg*4 + r] ------
        float sv[4][4];
        __builtin_amdgcn_s_setprio(1);
#pragma unroll
        for (int cg = 0; cg < 4; ++cg) {
            f32x4 a = (f32x4){0.f, 0.f, 0.f, 0.f};
#pragma unroll
            for (int kc = 0; kc < 4; ++kc) {
                int kb = (cg * 16 + lr) * 256 + ((kc * 64 + lg * 16) ^ swz);
                bf16x8 kf = *(const bf16x8*)(Kb + kb);
                a = __builtin_amdgcn_mfma_f32_16x16x32_bf16(kf, qf[kc], a, 0, 0, 0);
            }
#pragma unroll
            for (int r = 0; r < 4; ++r) sv[cg][r] = a[r];
        }
        __builtin_amdgcn_s_setprio(0);

        if (kt == qt) {                              // causal mask, diagonal tile
#pragma unroll
            for (int cg = 0; cg < 4; ++cg)
#pragma unroll
                for (int r = 0; r < 4; ++r)
                    if (cg * 16 + lg * 4 + r > w * 16 + lr) sv[cg][r] = -1e30f;
        }

        // ---- defer-max online softmax (lane-local row) -------------------
        float pml = sv[0][0];
#pragma unroll
        for (int cg = 0; cg < 4; ++cg)
#pragma unroll
            for (int r = 0; r < 4; ++r) pml = fmaxf(pml, sv[cg][r]);

        if (!__all(pml * SL2E <= mrun + 11.f)) {     // rare: true max + rescale
            float mx = pml;
            mx = fmaxf(mx, __shfl_xor(mx, 16, 64));
            mx = fmaxf(mx, __shfl_xor(mx, 32, 64));  // full row max (q = lr)
            float mn = fmaxf(mrun, mx * SL2E);
            float corr = exp2f(mrun - mn);
            mrun = mn;
            lrun *= corr;                            // lane-partial sum scales too
            float ca[4];
#pragma unroll
            for (int r = 0; r < 4; ++r)              // corr for accO rows q=lg*4+r
                ca[r] = __shfl(corr, (lg << 4) + lg * 4 + r, 64);
#pragma unroll
            for (int i = 0; i < 8; ++i)
#pragma unroll
                for (int r = 0; r < 4; ++r) accO[i][r] *= ca[r];
        }

        float psum = 0.f;
        float p[4][4];
#pragma unroll
        for (int cg = 0; cg < 4; ++cg)
#pragma unroll
            for (int r = 0; r < 4; ++r) {
                p[cg][r] = exp2f(fmaf(sv[cg][r], SL2E, -mrun));
                psum += p[cg][r];
            }
        lrun += psum;

        // pack P pairs -> b64 LDS writes (row q=lr, k = 16cg+4lg .. +3)
#pragma unroll
        for (int cg = 0; cg < 4; ++cg) {
            uint32_t w0, w1;
            asm("v_cvt_pk_bf16_f32 %0, %1, %2" : "=v"(w0) : "v"(p[cg][0]), "v"(p[cg][1]));
            asm("v_cvt_pk_bf16_f32 %0, %1, %2" : "=v"(w1) : "v"(p[cg][2]), "v"(p[cg][3]));
            uint2 pr; pr.x = w0; pr.y = w1;
            *(uint2*)((char*)Pw + lr * 128 + ((cg * 32 + lg * 8) ^ swz)) = pr;
        }

        asm volatile("" ::: "memory");               // order P stores before reads
        bf16x8 pf[2];
#pragma unroll
        for (int c = 0; c < 2; ++c)
            pf[c] = *(const bf16x8*)((char*)Pw + lr * 128 + ((c * 64 + lg * 16) ^ swz));

        __builtin_amdgcn_s_setprio(1);
#pragma unroll
        for (int ni = 0; ni < 8; ++ni)
#pragma unroll
            for (int c = 0; c < 2; ++c) {
                int vb = (ni * 16 + lr) * 128 + ((c * 64 + lg * 16) ^ swz);
                bf16x8 vf = *(const bf16x8*)(Vb + vb);
                accO[ni] = __builtin_amdgcn_mfma_f32_16x16x32_bf16(pf[c], vf, accO[ni], 0, 0, 0);
            }
        __builtin_amdgcn_s_setprio(0);

        __builtin_amdgcn_s_barrier();                // all reads done before next STAGE
    }

    // ---- epilogue ---------------------------------------------------------
    float lsum = lrun;
    lsum += __shfl_xor(lsum, 16, 64);
    lsum += __shfl_xor(lsum, 32, 64);                // full sum for row q = lr

    if (qt <= 15) {                                  // single chunk: direct AO
        float linv = 1.f / lsum;
        float inv[4];
#pragma unroll
        for (int r = 0; r < 4; ++r)
            inv[r] = __shfl(linv, (lg << 4) + lg * 4 + r, 64);
        const int b = h >> 3, n = h & 7;
#pragma unroll
        for (int ni = 0; ni < 8; ++ni)
#pragma unroll
            for (int r = 0; r < 4; ++r) {
                int trow = q0 + w * 16 + lg * 4 + r;
                AOg[((size_t)(b * 2048 + trow)) * 1024 + n * 128 + ni * 16 + lr] =
                    f2bf(accO[ni][r] * inv[r]);
            }
    } else {                                         // partial + (m, l)
        uint16_t* pb = pbuf + (size_t)slot * 8192;
#pragma unroll
        for (int ni = 0; ni < 8; ++ni)
#pragma unroll
            for (int r = 0; r < 4; ++r) {
                int row = w * 16 + lg * 4 + r;
                pb[row * 128 + ni * 16 + lr] = f2bf(accO[ni][r]);
            }
        if (lg == 0) {                               // one lane per (w,lr) row
            mlg[slot * 128 + w * 16 + lr]      = mrun;   // scaled-log2 domain
            mlg[slot * 128 + 64 + w * 16 + lr] = lsum;
        }
    }
}

// ------------------------------- split-K partial merge -> AO (qt >= 16, nc=2)
__global__ __launch_bounds__(256) void k_amerge(const uint16_t* __restrict__ pbuf,
                                                const float* __restrict__ mlg,
                                                uint16_t* __restrict__ AOg) {
    const int h = blockIdx.x, qt = 16 + blockIdx.y;  // qt in [16, 31]
    const int slot0 = h * 48 + 2 * (31 - qt);        // y = 2*(31-qt), +1
    const int tid = threadIdx.x;
    const int row = tid >> 2, dq = (tid & 3) * 32;

    float m0 = mlg[slot0 * 128 + row];
    float m1 = mlg[(slot0 + 1) * 128 + row];
    float M  = fmaxf(m0, m1);
    float w0 = exp2f(m0 - M), w1 = exp2f(m1 - M);
    float L  = mlg[slot0 * 128 + 64 + row] * w0 +
               mlg[(slot0 + 1) * 128 + 64 + row] * w1;
    float inv = 1.f / L;
    w0 *= inv; w1 *= inv;

    const u16x8* p0 = (const u16x8*)(pbuf + (size_t)slot0 * 8192 + row * 128 + dq);
    const u16x8* p1 = (const u16x8*)(pbuf + (size_t)(slot0 + 1) * 8192 + row * 128 + dq);
    const int b = h >> 3, n = h & 7;
    uint16_t* op = AOg + ((size_t)(b * 2048 + qt * 64 + row)) * 1024 + n * 128 + dq;
#pragma unroll
    for (int jj = 0; jj < 4; ++jj) {
        u16x8 a = p0[jj], c = p1[jj], v;
#pragma unroll
        for (int k = 0; k < 8; ++k)
            v[k] = f2bf(bf2f(a[k]) * w0 + bf2f(c[k]) * w1);
        ((u16x8*)op)[jj] = v;
    }
}

// -------------------- blade mixing epilogue (bf16 split-K partials summed)
__global__ __launch_bounds__(256) void k_mix(const uint16_t* __restrict__ out0,
                                             const uint16_t* __restrict__ out1,
                                             const float* __restrict__ alpha,
                                             float* __restrict__ fin) {
    constexpr int SI[42] = {1,1,1,1,1,1, 2,2,2,2,2,2, 3,3,3,3,3,3, 4,4,4,4,4,4,
                            5,5,5,5,5,5, 6,6,6,6,6,6, 7,7,7,7,7,7};
    constexpr int SJ[42] = {2,3,4,5,6,7, 1,3,4,5,6,7, 1,2,4,5,6,7, 1,2,3,5,6,7,
                            1,2,3,4,6,7, 1,2,3,4,5,7, 1,2,3,4,5,6};
    constexpr int TG[42] = {4,5,2,3,7,6, 4,6,1,7,3,5, 5,6,7,1,2,4, 2,1,7,6,5,3,
                            3,7,1,6,4,2, 7,3,2,5,4,1, 6,5,4,3,2,1};
    constexpr float SG[42] = {+1,+1,+1,+1,+1,+1, -1,+1,-1,-1,+1,-1, -1,-1,+1,-1,-1,+1,
                              -1,+1,+1,-1,+1,-1, -1,-1,+1,+1,-1,+1, +1,-1,+1,-1,+1,-1,
                              +1,-1,+1,-1,+1,-1};
    int idx = blockIdx.x * 256 + threadIdx.x;        // B*T * 32 d-quads
    int dq = (idx & 31) * 4, bt = idx >> 5;
    size_t base = (size_t)bt * 1024 + dq;
    float4 o[8], r[8];
#pragma unroll
    for (int hh = 0; hh < 8; ++hh) {
        ushort4 a = *(const ushort4*)&out0[base + hh * 128];
        ushort4 b = *(const ushort4*)&out1[base + hh * 128];
        o[hh] = make_float4(bf2f(a.x) + bf2f(b.x), bf2f(a.y) + bf2f(b.y),
                            bf2f(a.z) + bf2f(b.z), bf2f(a.w) + bf2f(b.w));
        r[hh] = o[hh];
    }
#pragma unroll
    for (int p = 0; p < 42; ++p) {
        float wgt = alpha[SI[p] * 8 + SJ[p]] * SG[p];
        r[TG[p]].x += wgt * o[SI[p]].x * o[SJ[p]].x;
        r[TG[p]].y += wgt * o[SI[p]].y * o[SJ[p]].y;
        r[TG[p]].z += wgt * o[SI[p]].z * o[SJ[p]].z;
        r[TG[p]].w += wgt * o[SI[p]].w * o[SJ[p]].w;
    }
#pragma unroll
    for (int hh = 0; hh < 8; ++hh) *(float4*)&fin[base + hh * 128] = r[hh];
}

// ---------------------------------------------------------------------------
extern "C" void kernel_launch(void* const* d_in, const int* in_sizes, int n_in,
                              void* d_out, int out_size, void* d_ws, size_t ws_size,
                              hipStream_t stream) {
    (void)in_sizes; (void)n_in; (void)out_size; (void)ws_size;
    const float* mv    = (const float*)d_in[0];
    const float* Wqkv  = (const float*)d_in[1];
    const float* Wo    = (const float*)d_in[2];
    const float* alpha = (const float*)d_in[3];
    float* outp = (float*)d_out;
    char* ws = (char*)d_ws;

    uint16_t* Xbf  = (uint16_t*)(ws + 0);            //  8 MB  [4096][1024]
    uint16_t* Wqt  = (uint16_t*)(ws + 8388608);      //  6 MB  [3072][1024]
    uint16_t* Wot  = (uint16_t*)(ws + 14680064);     //  2 MB  [1024][1024]
    uint16_t* Qr   = (uint16_t*)(ws + 41943040);     //  8 MB  [16][2048][128]
    uint16_t* Kr   = (uint16_t*)(ws + 50331648);     //  8 MB
    uint16_t* Vt   = (uint16_t*)(ws + 58720256);     //  8 MB  [16][128][2048]
    float*    ctab = (float*)(ws + 67108864);        // 0.5 MB
    float*    stab = (float*)(ws + 67633152);        // 0.5 MB
    uint16_t* AO   = (uint16_t*)(ws + 0);            // overlay (Xbf dead)
    float*    mlg  = (float*)(ws + 8388608);         // overlay (Wqt dead), 0.4 MB
    uint16_t* pbuf = (uint16_t*)(ws + 16777216);     // 12.6 MB partials
    uint16_t* outF0 = (uint16_t*)(ws + 16777216);    // overlay (pbuf dead), 8 MB bf16
    uint16_t* outF1 = (uint16_t*)(ws + 25165824);    // 8 MB bf16 (= outF0 + 4M elems)

    k_prep   <<<5632, 256, 0, stream>>>(mv, Wqkv, Wo, Xbf, Wqt, Wot, ctab, stab);
    k_gemmqkv<<<dim3(24, 32), 256, 0, stream>>>(Xbf, Wqt, ctab, stab, Qr, Kr, Vt);
    k_attn   <<<dim3(16, 48), 256, 0, stream>>>(Qr, Kr, Vt, pbuf, mlg, AO);
    k_amerge <<<dim3(16, 16), 256, 0, stream>>>(pbuf, mlg, AO);
    k_gemm2s <<<dim3(16, 32, 2), 256, 0, stream>>>(AO, Wot, outF0); // z=1 -> outF1
    k_mix    <<<512, 256, 0, stream>>>(outF0, outF1, alpha, outp);
}